// Round 6
// baseline (165.418 us; speedup 1.0000x reference)
//
#include <hip/hip_runtime.h>

// Self-attention (SAGAN-style), B=16, C=64, H=W=64. d8=8, d2=32, N=4096, M=1024.
// Round 13: per-wave restructure. r2-r5 showed attn pinned ~46-52us with
// MfmaUtil ~6 / VALUBusy ~45 / HBM ~11 / Occ ~31 -- structural latency
// exposure (4 load->use passes per wave + block barrier + scalar epilogue).
// Now: each wave owns one 16-q tile and sweeps ALL 16 m-chunks (K in-wave):
//  - 16-iter ping-pong prefetched loop (steady-state latency hiding)
//  - no __syncthreads, no cross-wave LDS reduce (rowsum = 2 shfl_xor)
//  - epilogue w_o conv via 4 MFMAs using pre-permuted bf16 w_oB (proj block
//    (0,0) emits it); o normalized in f32 before bf16 pack -> tiny error.
//  - LDS = 0 bytes.

#define B_   16
#define C_   64
#define HW_  4096
#define M_   1024

typedef __attribute__((ext_vector_type(8))) short bf16x8;
typedef __attribute__((ext_vector_type(4))) float f32x4;
typedef __attribute__((ext_vector_type(4))) _Float16 f16x4;

#define LOG2E 1.44269504088896340736f

__device__ __forceinline__ unsigned short f2bf(float f) {   // RNE
    union { float f; unsigned int u; } v; v.f = f;
    return (unsigned short)((v.u + 0x7FFFu + ((v.u >> 16) & 1u)) >> 16);
}
__device__ __forceinline__ unsigned int packh2(float a, float b) {  // f16 pair (RTZ)
    auto h = __builtin_amdgcn_cvt_pkrtz(a, b);      // __fp16 ext_vector(2)
    union { decltype(h) h; unsigned int u; } v;
    v.h = h;
    return v.u;
}
__device__ __forceinline__ unsigned int pack2t(float a, float b) {  // trunc bf16 pair
    union { float f; unsigned int u; } ua, ub; ua.f = a; ub.f = b;
    return (ua.u >> 16) | (ub.u & 0xFFFF0000u);
}

// ---------------------------------------------------------------------------
// proj: thetaH(B,N,8) f16 *log2e; phiH(B,1024,16) f16, cols 8..15 = 0;
// gTp(B,32,1024) bf16, m permuted per 32-block: ms=m&31,
// p = (m&~31) + ((ms>>2)&3)*8 + (ms>>4)*4 + (ms&3).
// Block (0,0) additionally emits w_oB[4][16][32] bf16: A-frag-layout w_o with
// k-column permutation c(k) = ((k>>2)&1)*16 + (k>>3)*4 + (k&3).
// ---------------------------------------------------------------------------
__global__ __launch_bounds__(256) void proj_kernel(
    const float* __restrict__ x,
    const float* __restrict__ w_theta, const float* __restrict__ b_theta,
    const float* __restrict__ w_phi,   const float* __restrict__ b_phi,
    const float* __restrict__ w_g,     const float* __restrict__ b_g,
    const float* __restrict__ w_o,
    unsigned short* __restrict__ thetaH,
    unsigned short* __restrict__ phiH,
    unsigned short* __restrict__ gTp,
    unsigned short* __restrict__ w_oB)
{
    __shared__ __align__(16) float x_l[64 * 132];   // [c][px] stride 132
    __shared__ float pool_l[128][41];               // 0..7 phi, 8..39 g

    const int tid = threadIdx.x;
    const int b   = blockIdx.y;
    const int rp  = blockIdx.x;          // row pair 0..31
    const int n0  = rp * 128;

    // stage x tile: 64 ch x 128 px, coalesced float4
    {
        const float4* src = (const float4*)(x + (size_t)b * C_ * HW_ + n0);
        #pragma unroll
        for (int j = 0; j < 8; j++) {
            int idx = tid + j * 256;
            int c = idx >> 5, p4 = idx & 31;
            float4 v = src[(size_t)c * (HW_ / 4) + p4];
            *(float4*)&x_l[c * 132 + p4 * 4] = v;
        }
    }
    __syncthreads();

    const int px = tid & 127;
    const int og = tid >> 7;             // wave-uniform half

    if (og == 0) {
        float th[8], ph[8], g0[8];
        #pragma unroll
        for (int o = 0; o < 8; o++) { th[o] = b_theta[o]; ph[o] = b_phi[o]; g0[o] = b_g[o]; }
        #pragma unroll 4
        for (int c = 0; c < C_; c++) {
            float xv = x_l[c * 132 + px];
            #pragma unroll
            for (int o = 0; o < 8; o++) th[o] += xv * w_theta[o * 64 + c];
            #pragma unroll
            for (int o = 0; o < 8; o++) ph[o] += xv * w_phi[o * 64 + c];
            #pragma unroll
            for (int o = 0; o < 8; o++) g0[o] += xv * w_g[o * 64 + c];
        }
        // theta: f16, pre-scaled by log2(e) so attn can use exp2 directly
        unsigned short* tout = thetaH + ((size_t)b * HW_ + n0 + px) * 8;
        uint4 tv;
        tv.x = packh2(th[0] * LOG2E, th[1] * LOG2E);
        tv.y = packh2(th[2] * LOG2E, th[3] * LOG2E);
        tv.z = packh2(th[4] * LOG2E, th[5] * LOG2E);
        tv.w = packh2(th[6] * LOG2E, th[7] * LOG2E);
        *(uint4*)tout = tv;
        #pragma unroll
        for (int o = 0; o < 8; o++) { pool_l[px][o] = ph[o]; pool_l[px][8 + o] = g0[o]; }
    } else {
        float gg[24];
        #pragma unroll
        for (int o = 0; o < 24; o++) gg[o] = b_g[8 + o];
        #pragma unroll 4
        for (int c = 0; c < C_; c++) {
            float xv = x_l[c * 132 + px];
            #pragma unroll
            for (int o = 0; o < 24; o++) gg[o] += xv * w_g[(8 + o) * 64 + c];
        }
        #pragma unroll
        for (int o = 0; o < 24; o++) pool_l[px][16 + o] = gg[o];
    }
    __syncthreads();

    // parallel 2x2 max-pool over all 256 threads:
    // j = pooled col (0..31), grp = tid>>5 (0..7) handles channels grp*5..grp*5+4
    {
        const int j   = tid & 31;
        const int grp = tid >> 5;
        const int p00 = 2 * j, p01 = 2 * j + 1, p10 = 64 + 2 * j, p11 = 65 + 2 * j;
        const int mq   = rp * 32 + j;
        const int pcol = rp * 32 + ((j >> 2) & 3) * 8 + (j >> 4) * 4 + (j & 3);
        #pragma unroll
        for (int k = 0; k < 5; k++) {
            const int ch = grp * 5 + k;          // 0..39 exactly
            float v = fmaxf(fmaxf(pool_l[p00][ch], pool_l[p01][ch]),
                            fmaxf(pool_l[p10][ch], pool_l[p11][ch]));
            if (ch < 8)
                ((_Float16*)phiH)[((size_t)b * M_ + mq) * 16 + ch] = (_Float16)v;
            else
                gTp[((size_t)b * 32 + (ch - 8)) * M_ + pcol] = f2bf(v);
        }
        // zero phi k-pads (cols 8..15): 32 m x 1 uint4
        if (tid < 32) {
            *(uint4*)((_Float16*)phiH + ((size_t)b * M_ + rp * 32 + tid) * 16 + 8) =
                make_uint4(0, 0, 0, 0);
        }
    }

    // w_oB: one block only; 2048 entries, 8 per thread
    if (rp == 0 && b == 0) {
        #pragma unroll
        for (int i = 0; i < 8; i++) {
            const int e   = tid * 8 + i;
            const int k   = e & 31;
            const int row = (e >> 5) & 15;
            const int cot = e >> 9;
            const int c   = ((k >> 2) & 1) * 16 + ((k >> 3) << 2) + (k & 3);
            w_oB[e] = f2bf(w_o[(cot * 16 + row) * 32 + c]);
        }
    }
}

// ---------------------------------------------------------------------------
// attn: block = 256 thr = 4 independent waves; wave owns 16 q rows
// (qb = blockIdx.x*64 + wv*16) and sweeps all 16 m-chunks of 64. Per chunk:
// 4 phi + 4 g loads (ping-pong prefetched), 4 score (16x16x16 f16) + 4 PV
// (16x16x32 bf16) MFMAs, 16 exp2/lane. P remap: S C-layout == PV B-frag with
// k=quad*8+j <-> m = s*32 + (j>>2)*16 + quad*4 + (j&3) (gTp pre-permuted).
// Rowsum completes in-wave (2 shfl_xor). Epilogue: o *= sg/rowsum in f32,
// pack bf16 (B-frag by construction), 4 MFMAs with w_oB, residual+bias.
// No LDS, no barriers.
// ---------------------------------------------------------------------------
__global__ __launch_bounds__(256, 4) void attn_kernel(
    const float* __restrict__ x,
    const unsigned short* __restrict__ thetaH,   // [b][n][8] f16, *log2e
    const unsigned short* __restrict__ phiH,     // [b][m][16] f16, cols 8..15 = 0
    const unsigned short* __restrict__ gTp,      // [b][c][1024] bf16, m-permuted
    const unsigned short* __restrict__ w_oB,     // [4][16][32] bf16, c-permuted
    const float* __restrict__ b_o,
    const float* __restrict__ sigma,
    float* __restrict__ out)
{
    const int tid   = threadIdx.x;
    const int b     = blockIdx.y;
    const int wv    = tid >> 6;
    const int lane  = tid & 63;
    const int ln15  = lane & 15;
    const int quad  = lane >> 4;
    const int wq    = blockIdx.x * 64 + wv * 16;   // wave's q base

    const _Float16* phiP = (const _Float16*)phiH + (size_t)b * M_ * 16;
    const unsigned short* gP = gTp + (size_t)b * 32 * M_;

    // theta B-frag (k = quad*4+j; quads 0-1 real, 2-3 zero)
    f16x4 th;
    {
        const _Float16* tp = (const _Float16*)thetaH
            + ((size_t)b * HW_ + wq + ln15) * 8 + (quad & 1) * 4;
        f16x4 t = *(const f16x4*)tp;
        const f16x4 z = {0, 0, 0, 0};
        th = (quad < 2) ? t : z;
    }

    #define LD_PHI(ch_, mt_) \
        (*(const f16x4*)(phiP + ((ch_) * 64 + (mt_) * 16 + ln15) * 16 + quad * 4))
    #define LD_G(ch_, h_, s_) \
        (*(const bf16x8*)(gP + (size_t)((h_) * 16 + ln15) * M_ + (ch_) * 64 + (s_) * 32 + quad * 8))

    f32x4 acc0 = {0.f, 0.f, 0.f, 0.f};   // c 0..15  (h=0), O^T partial
    f32x4 acc1 = {0.f, 0.f, 0.f, 0.f};   // c 16..31 (h=1)
    float rs_p = 0.f;

    // ping-pong buffers
    f16x4  pf[2][4];
    bf16x8 gf[2][4];                      // [buf][h*2+s]

    #pragma unroll
    for (int mt = 0; mt < 4; mt++) pf[0][mt] = LD_PHI(0, mt);
    gf[0][0] = LD_G(0, 0, 0); gf[0][1] = LD_G(0, 0, 1);
    gf[0][2] = LD_G(0, 1, 0); gf[0][3] = LD_G(0, 1, 1);

    #pragma unroll
    for (int ch = 0; ch < 16; ch++) {
        const int cur = ch & 1, nxt = cur ^ 1;
        if (ch < 15) {
            #pragma unroll
            for (int mt = 0; mt < 4; mt++) pf[nxt][mt] = LD_PHI(ch + 1, mt);
            gf[nxt][0] = LD_G(ch + 1, 0, 0); gf[nxt][1] = LD_G(ch + 1, 0, 1);
            gf[nxt][2] = LD_G(ch + 1, 1, 0); gf[nxt][3] = LD_G(ch + 1, 1, 1);
        }
        #pragma unroll
        for (int s = 0; s < 2; s++) {
            const f32x4 zc = {0.f, 0.f, 0.f, 0.f};
            f32x4 S0 = __builtin_amdgcn_mfma_f32_16x16x16f16(pf[cur][2 * s],     th, zc, 0, 0, 0);
            f32x4 S1 = __builtin_amdgcn_mfma_f32_16x16x16f16(pf[cur][2 * s + 1], th, zc, 0, 0, 0);
            float e0[4], e1[4];
            #pragma unroll
            for (int r = 0; r < 4; r++) {
                e0[r] = exp2f(S0[r]);            // theta pre-scaled by log2e
                e1[r] = exp2f(S1[r]);
                rs_p += e0[r] + e1[r];
            }
            union { bf16x8 v; unsigned int u[4]; } pb;
            pb.u[0] = pack2t(e0[0], e0[1]); pb.u[1] = pack2t(e0[2], e0[3]);
            pb.u[2] = pack2t(e1[0], e1[1]); pb.u[3] = pack2t(e1[2], e1[3]);
            acc0 = __builtin_amdgcn_mfma_f32_16x16x32_bf16(gf[cur][s],     pb.v, acc0, 0, 0, 0);
            acc1 = __builtin_amdgcn_mfma_f32_16x16x32_bf16(gf[cur][2 + s], pb.v, acc1, 0, 0, 0);
        }
    }
    #undef LD_PHI
    #undef LD_G

    // epilogue (all in-wave, no LDS): w_oB frags, rowsum, normalize, 4 MFMAs
    bf16x8 wf[4];
    #pragma unroll
    for (int t4 = 0; t4 < 4; t4++)
        wf[t4] = *(const bf16x8*)(w_oB + t4 * 512 + ln15 * 32 + quad * 8);

    float rs = rs_p;
    rs += __shfl_xor(rs, 16);
    rs += __shfl_xor(rs, 32);            // all lanes: rowsum for q = wq + ln15
    const float sg  = sigma[0];
    const float inv = sg / rs;

    union { bf16x8 v; unsigned int u[4]; } ob;   // normalized O as PV-style B-frag
    ob.u[0] = pack2t(acc0[0] * inv, acc0[1] * inv);
    ob.u[1] = pack2t(acc0[2] * inv, acc0[3] * inv);
    ob.u[2] = pack2t(acc1[0] * inv, acc1[1] * inv);
    ob.u[3] = pack2t(acc1[2] * inv, acc1[3] * inv);

    const f32x4 zc = {0.f, 0.f, 0.f, 0.f};
    const size_t xq = (size_t)b * C_ * HW_ + wq + ln15;
    #pragma unroll
    for (int t4 = 0; t4 < 4; t4++) {
        f32x4 oo = __builtin_amdgcn_mfma_f32_16x16x32_bf16(wf[t4], ob.v, zc, 0, 0, 0);
        #pragma unroll
        for (int r = 0; r < 4; r++) {
            const int co = t4 * 16 + quad * 4 + r;
            const size_t idx = xq + (size_t)co * HW_;
            out[idx] = x[idx] + oo[r] + sg * b_o[co];
        }
    }
}

// ---------------------------------------------------------------------------
extern "C" void kernel_launch(void* const* d_in, const int* in_sizes, int n_in,
                              void* d_out, int out_size, void* d_ws, size_t ws_size,
                              hipStream_t stream)
{
    const float* x       = (const float*)d_in[0];
    const float* w_theta = (const float*)d_in[1];
    const float* b_theta = (const float*)d_in[2];
    const float* w_phi   = (const float*)d_in[3];
    const float* b_phi   = (const float*)d_in[4];
    const float* w_g     = (const float*)d_in[5];
    const float* b_g     = (const float*)d_in[6];
    const float* w_o     = (const float*)d_in[7];
    const float* b_o     = (const float*)d_in[8];
    const float* sigma   = (const float*)d_in[9];
    float* out = (float*)d_out;

    // workspace: thetaH 1 MB (f16), phiH 0.5 MB (f16), gTp 1 MB (bf16), w_oB 4 KB
    unsigned short* thetaH = (unsigned short*)d_ws;
    unsigned short* phiH   = thetaH + (size_t)B_ * HW_ * 8;
    unsigned short* gTp    = phiH   + (size_t)B_ * M_ * 16;
    unsigned short* w_oB   = gTp    + (size_t)B_ * 32 * M_;

    proj_kernel<<<dim3(32, B_), 256, 0, stream>>>(
        x, w_theta, b_theta, w_phi, b_phi, w_g, b_g, w_o, thetaH, phiH, gTp, w_oB);
    attn_kernel<<<dim3(64, B_), 256, 0, stream>>>(
        x, thetaH, phiH, gTp, w_oB, b_o, sigma, out);
}

// Round 7
// 146.268 us; speedup vs baseline: 1.1309x; 1.1309x over previous
//
#include <hip/hip_runtime.h>

// Self-attention (SAGAN-style), B=16, C=64, H=W=64. d8=8, d2=32, N=4096, M=1024.
// Round 14: register-budget fix. r13's per-wave sweep was correct but
// __launch_bounds__(256,4) still made the allocator target 64 VGPR and spill
// the ping-pong state to scratch (FETCH 90MB / WRITE 167MB vs 16MB output).
// Only change: attn __launch_bounds__(256,2) -> 256-VGPR budget, pipeline
// stays in registers. Structure identical to r13: wave owns 16 q rows, sweeps
// 16 m-chunks ping-pong prefetched, no LDS, no barriers, MFMA epilogue.

#define B_   16
#define C_   64
#define HW_  4096
#define M_   1024

typedef __attribute__((ext_vector_type(8))) short bf16x8;
typedef __attribute__((ext_vector_type(4))) float f32x4;
typedef __attribute__((ext_vector_type(4))) _Float16 f16x4;

#define LOG2E 1.44269504088896340736f

__device__ __forceinline__ unsigned short f2bf(float f) {   // RNE
    union { float f; unsigned int u; } v; v.f = f;
    return (unsigned short)((v.u + 0x7FFFu + ((v.u >> 16) & 1u)) >> 16);
}
__device__ __forceinline__ unsigned int packh2(float a, float b) {  // f16 pair (RTZ)
    auto h = __builtin_amdgcn_cvt_pkrtz(a, b);      // __fp16 ext_vector(2)
    union { decltype(h) h; unsigned int u; } v;
    v.h = h;
    return v.u;
}
__device__ __forceinline__ unsigned int pack2t(float a, float b) {  // trunc bf16 pair
    union { float f; unsigned int u; } ua, ub; ua.f = a; ub.f = b;
    return (ua.u >> 16) | (ub.u & 0xFFFF0000u);
}

// ---------------------------------------------------------------------------
// proj: thetaH(B,N,8) f16 *log2e; phiH(B,1024,16) f16, cols 8..15 = 0;
// gTp(B,32,1024) bf16, m permuted per 32-block: ms=m&31,
// p = (m&~31) + ((ms>>2)&3)*8 + (ms>>4)*4 + (ms&3).
// Block (0,0) additionally emits w_oB[4][16][32] bf16: A-frag-layout w_o with
// k-column permutation c(k) = ((k>>2)&1)*16 + (k>>3)*4 + (k&3).
// ---------------------------------------------------------------------------
__global__ __launch_bounds__(256) void proj_kernel(
    const float* __restrict__ x,
    const float* __restrict__ w_theta, const float* __restrict__ b_theta,
    const float* __restrict__ w_phi,   const float* __restrict__ b_phi,
    const float* __restrict__ w_g,     const float* __restrict__ b_g,
    const float* __restrict__ w_o,
    unsigned short* __restrict__ thetaH,
    unsigned short* __restrict__ phiH,
    unsigned short* __restrict__ gTp,
    unsigned short* __restrict__ w_oB)
{
    __shared__ __align__(16) float x_l[64 * 132];   // [c][px] stride 132
    __shared__ float pool_l[128][41];               // 0..7 phi, 8..39 g

    const int tid = threadIdx.x;
    const int b   = blockIdx.y;
    const int rp  = blockIdx.x;          // row pair 0..31
    const int n0  = rp * 128;

    // stage x tile: 64 ch x 128 px, coalesced float4
    {
        const float4* src = (const float4*)(x + (size_t)b * C_ * HW_ + n0);
        #pragma unroll
        for (int j = 0; j < 8; j++) {
            int idx = tid + j * 256;
            int c = idx >> 5, p4 = idx & 31;
            float4 v = src[(size_t)c * (HW_ / 4) + p4];
            *(float4*)&x_l[c * 132 + p4 * 4] = v;
        }
    }
    __syncthreads();

    const int px = tid & 127;
    const int og = tid >> 7;             // wave-uniform half

    if (og == 0) {
        float th[8], ph[8], g0[8];
        #pragma unroll
        for (int o = 0; o < 8; o++) { th[o] = b_theta[o]; ph[o] = b_phi[o]; g0[o] = b_g[o]; }
        #pragma unroll 4
        for (int c = 0; c < C_; c++) {
            float xv = x_l[c * 132 + px];
            #pragma unroll
            for (int o = 0; o < 8; o++) th[o] += xv * w_theta[o * 64 + c];
            #pragma unroll
            for (int o = 0; o < 8; o++) ph[o] += xv * w_phi[o * 64 + c];
            #pragma unroll
            for (int o = 0; o < 8; o++) g0[o] += xv * w_g[o * 64 + c];
        }
        // theta: f16, pre-scaled by log2(e) so attn can use exp2 directly
        unsigned short* tout = thetaH + ((size_t)b * HW_ + n0 + px) * 8;
        uint4 tv;
        tv.x = packh2(th[0] * LOG2E, th[1] * LOG2E);
        tv.y = packh2(th[2] * LOG2E, th[3] * LOG2E);
        tv.z = packh2(th[4] * LOG2E, th[5] * LOG2E);
        tv.w = packh2(th[6] * LOG2E, th[7] * LOG2E);
        *(uint4*)tout = tv;
        #pragma unroll
        for (int o = 0; o < 8; o++) { pool_l[px][o] = ph[o]; pool_l[px][8 + o] = g0[o]; }
    } else {
        float gg[24];
        #pragma unroll
        for (int o = 0; o < 24; o++) gg[o] = b_g[8 + o];
        #pragma unroll 4
        for (int c = 0; c < C_; c++) {
            float xv = x_l[c * 132 + px];
            #pragma unroll
            for (int o = 0; o < 24; o++) gg[o] += xv * w_g[(8 + o) * 64 + c];
        }
        #pragma unroll
        for (int o = 0; o < 24; o++) pool_l[px][16 + o] = gg[o];
    }
    __syncthreads();

    // parallel 2x2 max-pool over all 256 threads:
    // j = pooled col (0..31), grp = tid>>5 (0..7) handles channels grp*5..grp*5+4
    {
        const int j   = tid & 31;
        const int grp = tid >> 5;
        const int p00 = 2 * j, p01 = 2 * j + 1, p10 = 64 + 2 * j, p11 = 65 + 2 * j;
        const int mq   = rp * 32 + j;
        const int pcol = rp * 32 + ((j >> 2) & 3) * 8 + (j >> 4) * 4 + (j & 3);
        #pragma unroll
        for (int k = 0; k < 5; k++) {
            const int ch = grp * 5 + k;          // 0..39 exactly
            float v = fmaxf(fmaxf(pool_l[p00][ch], pool_l[p01][ch]),
                            fmaxf(pool_l[p10][ch], pool_l[p11][ch]));
            if (ch < 8)
                ((_Float16*)phiH)[((size_t)b * M_ + mq) * 16 + ch] = (_Float16)v;
            else
                gTp[((size_t)b * 32 + (ch - 8)) * M_ + pcol] = f2bf(v);
        }
        // zero phi k-pads (cols 8..15): 32 m x 1 uint4
        if (tid < 32) {
            *(uint4*)((_Float16*)phiH + ((size_t)b * M_ + rp * 32 + tid) * 16 + 8) =
                make_uint4(0, 0, 0, 0);
        }
    }

    // w_oB: one block only; 2048 entries, 8 per thread
    if (rp == 0 && b == 0) {
        #pragma unroll
        for (int i = 0; i < 8; i++) {
            const int e   = tid * 8 + i;
            const int k   = e & 31;
            const int row = (e >> 5) & 15;
            const int cot = e >> 9;
            const int c   = ((k >> 2) & 1) * 16 + ((k >> 3) << 2) + (k & 3);
            w_oB[e] = f2bf(w_o[(cot * 16 + row) * 32 + c]);
        }
    }
}

// ---------------------------------------------------------------------------
// attn: block = 256 thr = 4 independent waves; wave owns 16 q rows
// (qb = blockIdx.x*64 + wv*16) and sweeps all 16 m-chunks of 64. Per chunk:
// 4 phi + 4 g loads (ping-pong prefetched), 4 score (16x16x16 f16) + 4 PV
// (16x16x32 bf16) MFMAs, 16 exp2/lane. P remap: S C-layout == PV B-frag with
// k=quad*8+j <-> m = s*32 + (j>>2)*16 + quad*4 + (j&3) (gTp pre-permuted).
// Rowsum completes in-wave (2 shfl_xor). Epilogue: o *= sg/rowsum in f32,
// pack bf16 (B-frag by construction), 4 MFMAs with w_oB, residual+bias.
// No LDS, no barriers. launch_bounds(256,2): 256-VGPR budget so the
// ping-pong pipeline stays in registers (r13's (256,4) spilled at 64).
// ---------------------------------------------------------------------------
__global__ __launch_bounds__(256, 2) void attn_kernel(
    const float* __restrict__ x,
    const unsigned short* __restrict__ thetaH,   // [b][n][8] f16, *log2e
    const unsigned short* __restrict__ phiH,     // [b][m][16] f16, cols 8..15 = 0
    const unsigned short* __restrict__ gTp,      // [b][c][1024] bf16, m-permuted
    const unsigned short* __restrict__ w_oB,     // [4][16][32] bf16, c-permuted
    const float* __restrict__ b_o,
    const float* __restrict__ sigma,
    float* __restrict__ out)
{
    const int tid   = threadIdx.x;
    const int b     = blockIdx.y;
    const int wv    = tid >> 6;
    const int lane  = tid & 63;
    const int ln15  = lane & 15;
    const int quad  = lane >> 4;
    const int wq    = blockIdx.x * 64 + wv * 16;   // wave's q base

    const _Float16* phiP = (const _Float16*)phiH + (size_t)b * M_ * 16;
    const unsigned short* gP = gTp + (size_t)b * 32 * M_;

    // theta B-frag (k = quad*4+j; quads 0-1 real, 2-3 zero)
    f16x4 th;
    {
        const _Float16* tp = (const _Float16*)thetaH
            + ((size_t)b * HW_ + wq + ln15) * 8 + (quad & 1) * 4;
        f16x4 t = *(const f16x4*)tp;
        const f16x4 z = {0, 0, 0, 0};
        th = (quad < 2) ? t : z;
    }

    #define LD_PHI(ch_, mt_) \
        (*(const f16x4*)(phiP + ((ch_) * 64 + (mt_) * 16 + ln15) * 16 + quad * 4))
    #define LD_G(ch_, h_, s_) \
        (*(const bf16x8*)(gP + (size_t)((h_) * 16 + ln15) * M_ + (ch_) * 64 + (s_) * 32 + quad * 8))

    f32x4 acc0 = {0.f, 0.f, 0.f, 0.f};   // c 0..15  (h=0), O^T partial
    f32x4 acc1 = {0.f, 0.f, 0.f, 0.f};   // c 16..31 (h=1)
    float rs_p = 0.f;

    // ping-pong buffers
    f16x4  pf[2][4];
    bf16x8 gf[2][4];                      // [buf][h*2+s]

    #pragma unroll
    for (int mt = 0; mt < 4; mt++) pf[0][mt] = LD_PHI(0, mt);
    gf[0][0] = LD_G(0, 0, 0); gf[0][1] = LD_G(0, 0, 1);
    gf[0][2] = LD_G(0, 1, 0); gf[0][3] = LD_G(0, 1, 1);

    #pragma unroll
    for (int ch = 0; ch < 16; ch++) {
        const int cur = ch & 1, nxt = cur ^ 1;
        if (ch < 15) {
            #pragma unroll
            for (int mt = 0; mt < 4; mt++) pf[nxt][mt] = LD_PHI(ch + 1, mt);
            gf[nxt][0] = LD_G(ch + 1, 0, 0); gf[nxt][1] = LD_G(ch + 1, 0, 1);
            gf[nxt][2] = LD_G(ch + 1, 1, 0); gf[nxt][3] = LD_G(ch + 1, 1, 1);
        }
        #pragma unroll
        for (int s = 0; s < 2; s++) {
            const f32x4 zc = {0.f, 0.f, 0.f, 0.f};
            f32x4 S0 = __builtin_amdgcn_mfma_f32_16x16x16f16(pf[cur][2 * s],     th, zc, 0, 0, 0);
            f32x4 S1 = __builtin_amdgcn_mfma_f32_16x16x16f16(pf[cur][2 * s + 1], th, zc, 0, 0, 0);
            float e0[4], e1[4];
            #pragma unroll
            for (int r = 0; r < 4; r++) {
                e0[r] = exp2f(S0[r]);            // theta pre-scaled by log2e
                e1[r] = exp2f(S1[r]);
                rs_p += e0[r] + e1[r];
            }
            union { bf16x8 v; unsigned int u[4]; } pb;
            pb.u[0] = pack2t(e0[0], e0[1]); pb.u[1] = pack2t(e0[2], e0[3]);
            pb.u[2] = pack2t(e1[0], e1[1]); pb.u[3] = pack2t(e1[2], e1[3]);
            acc0 = __builtin_amdgcn_mfma_f32_16x16x32_bf16(gf[cur][s],     pb.v, acc0, 0, 0, 0);
            acc1 = __builtin_amdgcn_mfma_f32_16x16x32_bf16(gf[cur][2 + s], pb.v, acc1, 0, 0, 0);
        }
    }
    #undef LD_PHI
    #undef LD_G

    // epilogue (all in-wave, no LDS): w_oB frags, rowsum, normalize, 4 MFMAs
    bf16x8 wf[4];
    #pragma unroll
    for (int t4 = 0; t4 < 4; t4++)
        wf[t4] = *(const bf16x8*)(w_oB + t4 * 512 + ln15 * 32 + quad * 8);

    float rs = rs_p;
    rs += __shfl_xor(rs, 16);
    rs += __shfl_xor(rs, 32);            // all lanes: rowsum for q = wq + ln15
    const float sg  = sigma[0];
    const float inv = sg / rs;

    union { bf16x8 v; unsigned int u[4]; } ob;   // normalized O as PV-style B-frag
    ob.u[0] = pack2t(acc0[0] * inv, acc0[1] * inv);
    ob.u[1] = pack2t(acc0[2] * inv, acc0[3] * inv);
    ob.u[2] = pack2t(acc1[0] * inv, acc1[1] * inv);
    ob.u[3] = pack2t(acc1[2] * inv, acc1[3] * inv);

    const f32x4 zc = {0.f, 0.f, 0.f, 0.f};
    const size_t xq = (size_t)b * C_ * HW_ + wq + ln15;
    #pragma unroll
    for (int t4 = 0; t4 < 4; t4++) {
        f32x4 oo = __builtin_amdgcn_mfma_f32_16x16x32_bf16(wf[t4], ob.v, zc, 0, 0, 0);
        #pragma unroll
        for (int r = 0; r < 4; r++) {
            const int co = t4 * 16 + quad * 4 + r;
            const size_t idx = xq + (size_t)co * HW_;
            out[idx] = x[idx] + oo[r] + sg * b_o[co];
        }
    }
}

// ---------------------------------------------------------------------------
extern "C" void kernel_launch(void* const* d_in, const int* in_sizes, int n_in,
                              void* d_out, int out_size, void* d_ws, size_t ws_size,
                              hipStream_t stream)
{
    const float* x       = (const float*)d_in[0];
    const float* w_theta = (const float*)d_in[1];
    const float* b_theta = (const float*)d_in[2];
    const float* w_phi   = (const float*)d_in[3];
    const float* b_phi   = (const float*)d_in[4];
    const float* w_g     = (const float*)d_in[5];
    const float* b_g     = (const float*)d_in[6];
    const float* w_o     = (const float*)d_in[7];
    const float* b_o     = (const float*)d_in[8];
    const float* sigma   = (const float*)d_in[9];
    float* out = (float*)d_out;

    // workspace: thetaH 1 MB (f16), phiH 0.5 MB (f16), gTp 1 MB (bf16), w_oB 4 KB
    unsigned short* thetaH = (unsigned short*)d_ws;
    unsigned short* phiH   = thetaH + (size_t)B_ * HW_ * 8;
    unsigned short* gTp    = phiH   + (size_t)B_ * M_ * 16;
    unsigned short* w_oB   = gTp    + (size_t)B_ * 32 * M_;

    proj_kernel<<<dim3(32, B_), 256, 0, stream>>>(
        x, w_theta, b_theta, w_phi, b_phi, w_g, b_g, w_o, thetaH, phiH, gTp, w_oB);
    attn_kernel<<<dim3(64, B_), 256, 0, stream>>>(
        x, thetaH, phiH, gTp, w_oB, b_o, sigma, out);
}

// Round 8
// 131.414 us; speedup vs baseline: 1.2587x; 1.1130x over previous
//
#include <hip/hip_runtime.h>

// Self-attention (SAGAN-style), B=16, C=64, H=W=64. d8=8, d2=32, N=4096, M=1024.
// Round 15: (a) attn = round-12 structure (best measured, 46us: q32/block,
// 4 waves split M, phi hoist + g ping-pong, LDS cross-wave reduce) with
// __launch_bounds__(256,3) so the prefetch pipeline gets registers (r5 showed
// VGPR=64 -> hoist was re-sunk; r7 showed the allocator DOES follow bounds).
// (b) proj reparallelized: 64-px blocks (grid 1024 = 4/CU), 4 balanced
// output groups x 12 ch (768 FMA/thread, was 1536), same math and layouts:
// thetaH(B,N,8) f16 *log2e; phiH(B,M,16) f16 cols 8..15=0; gTp(B,32,M) bf16
// m-permuted: ms=m&31, p=(m&~31)+((ms>>2)&3)*8+(ms>>4)*4+(ms&3).

#define B_   16
#define C_   64
#define HW_  4096
#define M_   1024

typedef __attribute__((ext_vector_type(8))) short bf16x8;
typedef __attribute__((ext_vector_type(4))) float f32x4;
typedef __attribute__((ext_vector_type(4))) _Float16 f16x4;

#define LOG2E 1.44269504088896340736f

__device__ __forceinline__ unsigned short f2bf(float f) {   // RNE
    union { float f; unsigned int u; } v; v.f = f;
    return (unsigned short)((v.u + 0x7FFFu + ((v.u >> 16) & 1u)) >> 16);
}
__device__ __forceinline__ unsigned int packh2(float a, float b) {  // f16 pair (RTZ)
    auto h = __builtin_amdgcn_cvt_pkrtz(a, b);      // __fp16 ext_vector(2)
    union { decltype(h) h; unsigned int u; } v;
    v.h = h;
    return v.u;
}
__device__ __forceinline__ unsigned int pack2t(float a, float b) {  // trunc bf16 pair
    union { float f; unsigned int u; } ua, ub; ua.f = a; ub.f = b;
    return (ua.u >> 16) | (ub.u & 0xFFFF0000u);
}

// ---------------------------------------------------------------------------
// proj: block = (bx = rp*2+hf, b); covers 2 rows x 32 cols = 64 px.
// 4 waves x 12 channels: og0 th0-7+ph0-3, og1 ph4-7+g0-7, og2 g8-19, og3 g20-31.
// ---------------------------------------------------------------------------
__global__ __launch_bounds__(256) void proj_kernel(
    const float* __restrict__ x,
    const float* __restrict__ w_theta, const float* __restrict__ b_theta,
    const float* __restrict__ w_phi,   const float* __restrict__ b_phi,
    const float* __restrict__ w_g,     const float* __restrict__ b_g,
    unsigned short* __restrict__ thetaH,
    unsigned short* __restrict__ phiH,
    unsigned short* __restrict__ gTp)
{
    __shared__ __align__(16) float x_l[64 * 68];    // [c][px] stride 68 (17.4 KB)
    __shared__ float pool_l[64][41];                // [px][ch] ph 0..7, g 8..39

    const int tid = threadIdx.x;
    const int b   = blockIdx.y;
    const int rp  = blockIdx.x >> 1;     // row pair 0..31
    const int hf  = blockIdx.x & 1;      // col half 0..1

    // stage x tile: 64 ch x (2 rows x 32 cols), coalesced float4
    {
        const float* src = x + (size_t)b * C_ * HW_ + (size_t)(2 * rp) * 64 + hf * 32;
        #pragma unroll
        for (int j = 0; j < 4; j++) {
            int idx = tid + j * 256;             // 0..1023 float4-slots
            int c   = idx >> 4, p4 = idx & 15;
            int row = p4 >> 3,  c4 = p4 & 7;
            float4 v = *(const float4*)(src + (size_t)c * HW_ + row * 64 + c4 * 4);
            *(float4*)&x_l[c * 68 + row * 32 + c4 * 4] = v;
        }
    }
    __syncthreads();

    const int px = tid & 63;
    const int og = tid >> 6;             // wave 0..3, uniform

    if (og == 0) {
        float th[8], ph[4];
        #pragma unroll
        for (int o = 0; o < 8; o++) th[o] = b_theta[o];
        #pragma unroll
        for (int o = 0; o < 4; o++) ph[o] = b_phi[o];
        #pragma unroll 8
        for (int c = 0; c < C_; c++) {
            float xv = x_l[c * 68 + px];
            #pragma unroll
            for (int o = 0; o < 8; o++) th[o] += xv * w_theta[o * 64 + c];
            #pragma unroll
            for (int o = 0; o < 4; o++) ph[o] += xv * w_phi[o * 64 + c];
        }
        const int row = px >> 5, col = px & 31;
        const int n   = (2 * rp + row) * 64 + hf * 32 + col;
        unsigned short* tout = thetaH + ((size_t)b * HW_ + n) * 8;
        uint4 tv;
        tv.x = packh2(th[0] * LOG2E, th[1] * LOG2E);
        tv.y = packh2(th[2] * LOG2E, th[3] * LOG2E);
        tv.z = packh2(th[4] * LOG2E, th[5] * LOG2E);
        tv.w = packh2(th[6] * LOG2E, th[7] * LOG2E);
        *(uint4*)tout = tv;
        #pragma unroll
        for (int o = 0; o < 4; o++) pool_l[px][o] = ph[o];
    } else if (og == 1) {
        float ph[4], gg[8];
        #pragma unroll
        for (int o = 0; o < 4; o++) ph[o] = b_phi[4 + o];
        #pragma unroll
        for (int o = 0; o < 8; o++) gg[o] = b_g[o];
        #pragma unroll 8
        for (int c = 0; c < C_; c++) {
            float xv = x_l[c * 68 + px];
            #pragma unroll
            for (int o = 0; o < 4; o++) ph[o] += xv * w_phi[(4 + o) * 64 + c];
            #pragma unroll
            for (int o = 0; o < 8; o++) gg[o] += xv * w_g[o * 64 + c];
        }
        #pragma unroll
        for (int o = 0; o < 4; o++) pool_l[px][4 + o] = ph[o];
        #pragma unroll
        for (int o = 0; o < 8; o++) pool_l[px][8 + o] = gg[o];
    } else if (og == 2) {
        float gg[12];
        #pragma unroll
        for (int o = 0; o < 12; o++) gg[o] = b_g[8 + o];
        #pragma unroll 8
        for (int c = 0; c < C_; c++) {
            float xv = x_l[c * 68 + px];
            #pragma unroll
            for (int o = 0; o < 12; o++) gg[o] += xv * w_g[(8 + o) * 64 + c];
        }
        #pragma unroll
        for (int o = 0; o < 12; o++) pool_l[px][16 + o] = gg[o];
    } else {
        float gg[12];
        #pragma unroll
        for (int o = 0; o < 12; o++) gg[o] = b_g[20 + o];
        #pragma unroll 8
        for (int c = 0; c < C_; c++) {
            float xv = x_l[c * 68 + px];
            #pragma unroll
            for (int o = 0; o < 12; o++) gg[o] += xv * w_g[(20 + o) * 64 + c];
        }
        #pragma unroll
        for (int o = 0; o < 12; o++) pool_l[px][28 + o] = gg[o];
    }
    __syncthreads();

    // 2x2 max-pool: j = pooled col 0..15 (this half), 10 groups x 4 channels
    {
        const int j = tid & 15, grp = tid >> 4;
        if (grp < 10) {
            const int jj   = hf * 16 + j;
            const int mq   = rp * 32 + jj;
            const int pcol = rp * 32 + ((jj >> 2) & 3) * 8 + (jj >> 4) * 4 + (jj & 3);
            #pragma unroll
            for (int k = 0; k < 4; k++) {
                const int ch = grp * 4 + k;          // 0..39
                float v = fmaxf(fmaxf(pool_l[2 * j][ch],      pool_l[2 * j + 1][ch]),
                                fmaxf(pool_l[32 + 2 * j][ch], pool_l[33 + 2 * j][ch]));
                if (ch < 8)
                    ((_Float16*)phiH)[((size_t)b * M_ + mq) * 16 + ch] = (_Float16)v;
                else
                    gTp[((size_t)b * 32 + (ch - 8)) * M_ + pcol] = f2bf(v);
            }
        }
        // zero phi k-pads (cols 8..15) for this block's 16 m values
        if (tid < 16) {
            *(uint4*)((_Float16*)phiH + ((size_t)b * M_ + rp * 32 + hf * 16 + tid) * 16 + 8) =
                make_uint4(0, 0, 0, 0);
        }
    }
}

// ---------------------------------------------------------------------------
// attn (round-12 structure, bounds (256,3)): block = (batch, 32-q tile),
// 256 thr = 4 waves, grid 128x16 = 2048 blocks. Wave wv owns m-chunks
// wv*4..wv*4+3. All 16 phi frags hoisted; g frags ping-pong prefetched.
// Per chunk: 8 score (16x16x16 f16) + 8 PV (16x16x32 bf16) MFMAs, 32 exp2.
// P remap: S C-layout == PV B-frag, k=quad*8+j <-> m=s*32+(j>>2)*16+quad*4+(j&3).
// Partial O^T / rowsum per wave; cross-wave reduce in epilogue (8 thr/q).
// ---------------------------------------------------------------------------
__global__ __launch_bounds__(256, 3) void attn_kernel(
    const float* __restrict__ x,
    const unsigned short* __restrict__ thetaH,   // [b][n][8] f16, *log2e
    const unsigned short* __restrict__ phiH,     // [b][m][16] f16, cols 8..15 = 0
    const unsigned short* __restrict__ gTp,      // [b][c][1024] bf16, m-permuted
    const float* __restrict__ w_o, const float* __restrict__ b_o,
    const float* __restrict__ sigma,
    float* __restrict__ out)
{
    __shared__ float Op_l[4][32 * 33];   // [wv][q][c] partial O  (16.9 KB)
    __shared__ float rs_l[4][32];        // [wv][q] partial rowsums

    const int tid   = threadIdx.x;
    const int b     = blockIdx.y;
    const int qbase = blockIdx.x * 32;
    const int wv    = tid >> 6;
    const int lane  = tid & 63;
    const int ln15  = lane & 15;
    const int quad  = lane >> 4;

    const _Float16* phiP = (const _Float16*)phiH + (size_t)b * M_ * 16;
    const unsigned short* gP = gTp + (size_t)b * 32 * M_;

    // theta B-frags for the 2 q-tiles (k = quad*4+j, quads 0-1 real)
    f16x4 th[2];
    {
        const f16x4 z = {0, 0, 0, 0};
        #pragma unroll
        for (int qt = 0; qt < 2; qt++) {
            const _Float16* tp = (const _Float16*)thetaH
                + ((size_t)b * HW_ + qbase + qt * 16 + ln15) * 8 + (quad & 1) * 4;
            f16x4 t = *(const f16x4*)tp;
            th[qt] = (quad < 2) ? t : z;
        }
    }

    #define LD_PHI(ch_, mt_) \
        (*(const f16x4*)(phiP + ((ch_) * 64 + (mt_) * 16 + ln15) * 16 + quad * 4))
    #define LD_G(ch_, h_, s_) \
        (*(const bf16x8*)(gP + (size_t)((h_) * 16 + ln15) * M_ + (ch_) * 64 + (s_) * 32 + quad * 8))

    // hoist ALL phi fragment loads: 16 independent 8B loads in flight (32 VGPR)
    f16x4 pf[4][4];
    #pragma unroll
    for (int wc = 0; wc < 4; wc++)
        #pragma unroll
        for (int mt = 0; mt < 4; mt++) pf[wc][mt] = LD_PHI(wv * 4 + wc, mt);

    // g ping-pong: preload chunk 0
    bf16x8 g00 = LD_G(wv * 4, 0, 0), g01 = LD_G(wv * 4, 0, 1);
    bf16x8 g10 = LD_G(wv * 4, 1, 0), g11 = LD_G(wv * 4, 1, 1);

    f32x4 acc[2][2];                     // [c-half][q-tile], O^T partial
    #pragma unroll
    for (int h = 0; h < 2; h++)
        #pragma unroll
        for (int qt = 0; qt < 2; qt++) acc[h][qt] = (f32x4){0.f, 0.f, 0.f, 0.f};
    float rs_p[2] = {0.f, 0.f};

    #pragma unroll
    for (int wc = 0; wc < 4; wc++) {
        // prefetch next chunk's g frags before consuming current (depth-1)
        bf16x8 n00, n01, n10, n11;
        if (wc < 3) {
            const int nch = wv * 4 + wc + 1;
            n00 = LD_G(nch, 0, 0); n01 = LD_G(nch, 0, 1);
            n10 = LD_G(nch, 1, 0); n11 = LD_G(nch, 1, 1);
        }

        #pragma unroll
        for (int s = 0; s < 2; s++) {
            const bf16x8 gh0 = (s == 0) ? g00 : g01;
            const bf16x8 gh1 = (s == 0) ? g10 : g11;
            #pragma unroll
            for (int qt = 0; qt < 2; qt++) {
                const f32x4 zc = {0.f, 0.f, 0.f, 0.f};
                f32x4 S0 = __builtin_amdgcn_mfma_f32_16x16x16f16(pf[wc][2 * s],     th[qt], zc, 0, 0, 0);
                f32x4 S1 = __builtin_amdgcn_mfma_f32_16x16x16f16(pf[wc][2 * s + 1], th[qt], zc, 0, 0, 0);
                float e0[4], e1[4];
                #pragma unroll
                for (int r = 0; r < 4; r++) {
                    e0[r] = exp2f(S0[r]);        // theta pre-scaled by log2e
                    e1[r] = exp2f(S1[r]);
                    rs_p[qt] += e0[r] + e1[r];
                }
                union { bf16x8 v; unsigned int u[4]; } pb;
                pb.u[0] = pack2t(e0[0], e0[1]); pb.u[1] = pack2t(e0[2], e0[3]);
                pb.u[2] = pack2t(e1[0], e1[1]); pb.u[3] = pack2t(e1[2], e1[3]);
                acc[0][qt] = __builtin_amdgcn_mfma_f32_16x16x32_bf16(gh0, pb.v, acc[0][qt], 0, 0, 0);
                acc[1][qt] = __builtin_amdgcn_mfma_f32_16x16x32_bf16(gh1, pb.v, acc[1][qt], 0, 0, 0);
            }
        }
        if (wc < 3) { g00 = n00; g01 = n01; g10 = n10; g11 = n11; }
    }
    #undef LD_PHI
    #undef LD_G

    // rowsum partials: reduce over quads (m-rows) within the wave
    {
        float v[2];
        #pragma unroll
        for (int qt = 0; qt < 2; qt++) {
            float t = rs_p[qt];
            t += __shfl_xor(t, 16);
            t += __shfl_xor(t, 32);
            v[qt] = t;
        }
        if (quad == 0) {
            #pragma unroll
            for (int qt = 0; qt < 2; qt++) rs_l[wv][qt * 16 + ln15] = v[qt];
        }
    }
    // O^T partials -> LDS: lane owns col q=qt*16+ln15, rows c=h*16+quad*4+r
    #pragma unroll
    for (int h = 0; h < 2; h++)
        #pragma unroll
        for (int qt = 0; qt < 2; qt++)
            #pragma unroll
            for (int r = 0; r < 4; r++)
                Op_l[wv][(qt * 16 + ln15) * 33 + h * 16 + quad * 4 + r] = acc[h][qt][r];
    __syncthreads();

    // epilogue: cross-wave reduce + normalize + w_o conv + bias + residual.
    // 8 threads per q (grp = tid>>5), each handles 8 output channels.
    const int q   = tid & 31;
    const int grp = tid >> 5;
    const float rowsum = rs_l[0][q] + rs_l[1][q] + rs_l[2][q] + rs_l[3][q];
    const float sg  = sigma[0];
    const float inv = sg / rowsum;
    float o[32];
    #pragma unroll
    for (int c = 0; c < 32; c++)
        o[c] = Op_l[0][q * 33 + c] + Op_l[1][q * 33 + c]
             + Op_l[2][q * 33 + c] + Op_l[3][q * 33 + c];
    const size_t xb = (size_t)b * C_ * HW_ + qbase + q;
    #pragma unroll
    for (int k = 0; k < 8; k++) {
        const int co = grp * 8 + k;
        float t = 0.f;
        #pragma unroll
        for (int c = 0; c < 32; c++) t += w_o[co * 32 + c] * o[c];
        out[xb + (size_t)co * HW_] = x[xb + (size_t)co * HW_] + t * inv + sg * b_o[co];
    }
}

// ---------------------------------------------------------------------------
extern "C" void kernel_launch(void* const* d_in, const int* in_sizes, int n_in,
                              void* d_out, int out_size, void* d_ws, size_t ws_size,
                              hipStream_t stream)
{
    const float* x       = (const float*)d_in[0];
    const float* w_theta = (const float*)d_in[1];
    const float* b_theta = (const float*)d_in[2];
    const float* w_phi   = (const float*)d_in[3];
    const float* b_phi   = (const float*)d_in[4];
    const float* w_g     = (const float*)d_in[5];
    const float* b_g     = (const float*)d_in[6];
    const float* w_o     = (const float*)d_in[7];
    const float* b_o     = (const float*)d_in[8];
    const float* sigma   = (const float*)d_in[9];
    float* out = (float*)d_out;

    // workspace: thetaH 1 MB (f16), phiH 0.5 MB (f16), gTp 1 MB (bf16)
    unsigned short* thetaH = (unsigned short*)d_ws;
    unsigned short* phiH   = thetaH + (size_t)B_ * HW_ * 8;
    unsigned short* gTp    = phiH   + (size_t)B_ * M_ * 16;

    proj_kernel<<<dim3(64, B_), 256, 0, stream>>>(
        x, w_theta, b_theta, w_phi, b_phi, w_g, b_g, thetaH, phiH, gTp);
    attn_kernel<<<dim3(128, B_), 256, 0, stream>>>(
        x, thetaH, phiH, gTp, w_o, b_o, sigma, out);
}